// Round 2
// 798.806 us; speedup vs baseline: 1.0409x; 1.0409x over previous
//
#include <hip/hip_runtime.h>

// B=4, S=2048, E=2048, H=16, D=128, full-head rope. f32 I/O, bf16 MFMA inside.
// Memory plan:
//   d_out: xb [0,32MiB) -> later ctx (same region); Qb [32,64MiB)
//   ws:    Kb [0,32), Vt [32,64), optional Wq_bf [64,88), Wo_bf [88,96)
//   GEMM2 -> f32 ws[0,64MiB), D2D copy to d_out.
// LDS tiles staged by global_load_lds are XOR-swizzled (chunk ^= row&7) to
// break the 16-way bank conflicts of unpadded 128B-stride rows (r6 counters).
// r9 (bisect of crashed r8): keep r7-proven attn compute (mfma(Q,K), shuffle
// softmax, padded P); add ONLY: paired q-tiles (qt,15-qt) for uniform work,
// async+swizzled V^T staging, wave-uniform masked-tile skip, setprio around
// MFMA, scale folded into rope(Q). Swapped-softmax deferred to next round.

using frag_ab = __attribute__((ext_vector_type(8))) short;   // 8 bf16 = 4 VGPRs
using frag_cd = __attribute__((ext_vector_type(4))) float;   // 4 f32 acc

__device__ __forceinline__ float b2f(unsigned short u) {
  union { unsigned int i; float f; } v; v.i = ((unsigned int)u) << 16; return v.f;
}
__device__ __forceinline__ unsigned short f2b(float f) {
  union { float f; unsigned int i; } v; v.f = f;
  unsigned int r = v.i + 0x7FFFu + ((v.i >> 16) & 1u);   // RNE
  return (unsigned short)(r >> 16);
}
__device__ __forceinline__ unsigned int pack2(float a, float b) {
  return (unsigned int)f2b(a) | ((unsigned int)f2b(b) << 16);
}
__device__ __forceinline__ void gload16(const unsigned short* g, unsigned short* l) {
  __builtin_amdgcn_global_load_lds(
      (const __attribute__((address_space(1))) unsigned int*)g,
      (__attribute__((address_space(3))) unsigned int*)l, 16, 0, 0);
}

// ---------------------------------------------------------------------------
__global__ __launch_bounds__(256)
void cvt_f32_bf16(const float* __restrict__ in, unsigned short* __restrict__ out) {
  long i = (long)(blockIdx.x * 256 + threadIdx.x) * 8;
  float4 a = *(const float4*)&in[i];
  float4 b = *(const float4*)&in[i + 4];
  uint4 p;
  p.x = pack2(a.x, a.y); p.y = pack2(a.z, a.w);
  p.z = pack2(b.x, b.y); p.w = pack2(b.z, b.w);
  *(uint4*)&out[i] = p;
}

// ---------------------------------------------------------------------------
// Shared GEMM staging (128x64 bf16 tile, XOR-swizzled chunks).
// A always bf16 via global_load_lds. B: bf16 async if Bbf, else f32 inline cvt.
// Fragment read: phys chunk = (quad + kk/8) ^ (l16 & 7).
// ---------------------------------------------------------------------------
__device__ __forceinline__ void stage_a_async(const unsigned short* A, unsigned short* As,
                                              int row0, int k0, int wave, int lane, int ldk) {
#pragma unroll
  for (int i = 0; i < 4; i++) {
    int rbase = wave * 32 + i * 8;
    int r = rbase + (lane >> 3);
    int srcc = (lane & 7) ^ (r & 7);
    gload16(&A[(long)(row0 + r) * ldk + k0 + srcc * 8], &As[rbase * 64]);
  }
}
__device__ __forceinline__ void stage_b_cvt(const float* Bw, unsigned short* Bs,
                                            int row0, int k0, int tid) {
#pragma unroll
  for (int i = 0; i < 4; i++) {
    int c = tid + i * 256;                 // chunk id in [0,1024)
    int r = c >> 3, ch = c & 7;
    const float* src = &Bw[(long)(row0 + r) * 2048 + k0 + ch * 8];
    float4 v0 = *(const float4*)src;
    float4 v1 = *(const float4*)(src + 4);
    uint4 p;
    p.x = pack2(v0.x, v0.y); p.y = pack2(v0.z, v0.w);
    p.z = pack2(v1.x, v1.y); p.w = pack2(v1.z, v1.w);
    *(uint4*)&Bs[r * 64 + ((ch ^ (r & 7)) * 8)] = p;
  }
}

// ---------------------------------------------------------------------------
// GEMM1: qkv = xb @ W^T + bias -> Q (B,H,S,D), K (B,H,S,D), V^T (B,H,D,S)
// ---------------------------------------------------------------------------
__global__ __launch_bounds__(256)
void gemm_qkv(const unsigned short* __restrict__ A,    // xb (8192,2048) bf16
              const float* __restrict__ Bw,            // wqkv_w f32
              const unsigned short* __restrict__ Bbf,  // wqkv_w bf16 or null
              const float* __restrict__ bias,
              unsigned short* __restrict__ Qb,
              unsigned short* __restrict__ Kb,
              unsigned short* __restrict__ Vt) {
  __shared__ __align__(16) unsigned short As[128 * 64];
  __shared__ __align__(16) unsigned short Bs[128 * 64];
  const int tid  = threadIdx.x;
  const int wave = tid >> 6, lane = tid & 63;
  const int quad = lane >> 4, l16 = lane & 15;
  const int wm = (wave & 1) * 64, wn = (wave >> 1) * 64;
  const int row0A = blockIdx.x * 128;
  const int row0B = blockIdx.y * 128;

  frag_cd acc[4][4];
#pragma unroll
  for (int i = 0; i < 4; i++)
#pragma unroll
    for (int j = 0; j < 4; j++) acc[i][j] = (frag_cd){0.f, 0.f, 0.f, 0.f};

  for (int k0 = 0; k0 < 2048; k0 += 64) {
    stage_a_async(A, As, row0A, k0, wave, lane, 2048);
    if (Bbf) stage_a_async(Bbf, Bs, row0B, k0, wave, lane, 2048);
    else     stage_b_cvt(Bw, Bs, row0B, k0, tid);
    __syncthreads();
#pragma unroll
    for (int kk = 0; kk < 64; kk += 32) {
      frag_ab af[4], bf[4];
#pragma unroll
      for (int mi = 0; mi < 4; mi++) {
        int row = wm + mi * 16 + l16;
        af[mi] = *(const frag_ab*)&As[row * 64 + (((quad + (kk >> 3)) ^ (l16 & 7)) * 8)];
      }
#pragma unroll
      for (int ni = 0; ni < 4; ni++) {
        int row = wn + ni * 16 + l16;
        bf[ni] = *(const frag_ab*)&Bs[row * 64 + (((quad + (kk >> 3)) ^ (l16 & 7)) * 8)];
      }
#pragma unroll
      for (int mi = 0; mi < 4; mi++)
#pragma unroll
        for (int ni = 0; ni < 4; ni++)
          acc[mi][ni] = __builtin_amdgcn_mfma_f32_16x16x32_bf16(af[mi], bf[ni], acc[mi][ni], 0, 0, 0);
    }
    __syncthreads();
  }
  // scatter epilogue (C/D layout: col=l16, row=quad*4+r; m89-verified)
#pragma unroll
  for (int ni = 0; ni < 4; ni++) {
    int col  = row0B + wn + ni * 16 + l16;
    int h    = col / 384;
    int rem  = col - h * 384;
    int slot = rem >> 7;
    int d    = rem & 127;
    float bv = bias[col];
#pragma unroll
    for (int mi = 0; mi < 4; mi++) {
#pragma unroll
      for (int r = 0; r < 4; r++) {
        int row = row0A + wm + mi * 16 + quad * 4 + r;
        int b = row >> 11, s = row & 2047;
        unsigned short val = f2b(acc[mi][ni][r] + bv);
        if (slot == 0)      Qb[((long)(b * 16 + h) * 2048 + s) * 128 + d] = val;
        else if (slot == 1) Kb[((long)(b * 16 + h) * 2048 + s) * 128 + d] = val;
        else                Vt[((long)(b * 16 + h) * 128 + d) * 2048 + s] = val;
      }
    }
  }
}

// ---------------------------------------------------------------------------
// rope in place; attention scale 1/sqrt(128) folded into Q here (free VALU).
// ---------------------------------------------------------------------------
__global__ __launch_bounds__(256)
void rope_inplace(unsigned short* __restrict__ Qb, unsigned short* __restrict__ Kb) {
  int wid  = blockIdx.x * 4 + (threadIdx.x >> 6);
  int j    = threadIdx.x & 63;
  int part = wid & 1;
  int s    = (wid >> 1) & 2047;
  int bh   = wid >> 12;
  unsigned short* buf = part ? Kb : Qb;
  long base = ((long)bh * 2048 + s) * 128;
  unsigned int pr = *(const unsigned int*)&buf[base + 2 * j];
  float x1 = b2f((unsigned short)(pr & 0xFFFFu));
  float x2 = b2f((unsigned short)(pr >> 16));
  float inv = powf(10000.0f, -(float)(2 * j) / 128.0f);
  float ang = (float)s * inv;
  float sn, cs;
  sincosf(ang, &sn, &cs);
  float sc = part ? 1.0f : 0.08838834764831845f;   // Q pre-scaled for attn
  cs *= sc; sn *= sc;
  buf[base + j]      = f2b(x1 * cs - x2 * sn);
  buf[base + 64 + j] = f2b(x1 * sn + x2 * cs);
}

// ---------------------------------------------------------------------------
// Causal flash attention. Q,K (B,H,S,D) with Q pre-scaled; V^T (B,H,D,S).
// ctx -> (B,S,E) bf16.
// r7-proven compute path (mfma(Q,K), shuffle softmax, padded P). New in r9:
// each block does TWO q-tiles (qt, 15-qt) -> uniform 34 kv-tiles/block,
// 512 blocks = 2/CU exact; V^T async-staged with chunk^(row&7) swizzle;
// wave-uniform skip of fully-masked tiles; setprio around MFMA clusters.
// ---------------------------------------------------------------------------
__global__ __launch_bounds__(256)
void attn_fwd(const unsigned short* __restrict__ Q,
              const unsigned short* __restrict__ K,
              const unsigned short* __restrict__ Vt,
              unsigned short* __restrict__ ctx) {
  __shared__ __align__(16) unsigned short Ks[64 * 128];   // 16-chunk XOR swizzle
  __shared__ __align__(16) unsigned short Vs[128 * 64];   // 8-chunk XOR swizzle
  __shared__ __align__(16) unsigned short Ps[4][32 * 72]; // per-wave P, padded
  const int bh = blockIdx.x;
  const int tid = threadIdx.x;
  const int wave = tid >> 6, lane = tid & 63;
  const int quad = lane >> 4, l16 = lane & 15;
  const long base  = (long)bh * 2048 * 128;
  const long vbase = (long)bh * 262144;
  const int b = bh >> 4, h = bh & 15;
  unsigned short* pw = &Ps[wave][0];

  for (int pass = 0; pass < 2; ++pass) {
    const int qt = pass ? (15 - blockIdx.y) : blockIdx.y;
    const int q0 = qt * 128 + wave * 32;

    frag_ab qf[2][4];
#pragma unroll
    for (int mi = 0; mi < 2; mi++)
#pragma unroll
      for (int ks = 0; ks < 4; ks++)
        qf[mi][ks] = *(const frag_ab*)&Q[base + (long)(q0 + mi * 16 + l16) * 128 + ks * 32 + quad * 8];

    frag_cd o[2][8];
#pragma unroll
    for (int mi = 0; mi < 2; mi++)
#pragma unroll
      for (int ni = 0; ni < 8; ni++) o[mi][ni] = (frag_cd){0.f, 0.f, 0.f, 0.f};
    float m_i[2][4], l_i[2][4];
#pragma unroll
    for (int mi = 0; mi < 2; mi++)
#pragma unroll
      for (int r = 0; r < 4; r++) { m_i[mi][r] = -1.0e30f; l_i[mi][r] = 0.f; }

    const int kv_end = qt * 128 + 128;
    for (int kv0 = 0; kv0 < kv_end; kv0 += 64) {
      __syncthreads();
      // K: 64x128, 16-chunk XOR swizzle, async (16 x 1KB stages)
#pragma unroll
      for (int i = 0; i < 4; i++) {
        int rbase = (wave * 4 + i) * 4;          // 4 rows per stage
        int r = rbase + (lane >> 4);
        int srcc = (lane & 15) ^ (r & 15);
        gload16(&K[base + (long)(kv0 + r) * 128 + srcc * 8], &Ks[rbase * 128]);
      }
      // V^T: 128x64, 8-chunk XOR swizzle, async (16 x 1KB stages)
#pragma unroll
      for (int i = 0; i < 4; i++) {
        int rbase = wave * 32 + i * 8;           // 8 rows per stage
        int r = rbase + (lane >> 3);
        int srcc = (lane & 7) ^ (r & 7);
        gload16(&Vt[vbase + (long)r * 2048 + kv0 + srcc * 8], &Vs[rbase * 64]);
      }
      __syncthreads();

      if (kv0 <= q0 + 31) {                 // else: fully masked for this wave
        // S = Q @ K^T (32x64 per wave); Q pre-scaled, mask to -10000 (as ref)
        float p[2][4][4];
        __builtin_amdgcn_s_setprio(1);
#pragma unroll
        for (int nj = 0; nj < 4; nj++) {
          frag_ab kf[4];
          int row = nj * 16 + l16;
#pragma unroll
          for (int ks = 0; ks < 4; ks++)
            kf[ks] = *(const frag_ab*)&Ks[row * 128 + (((ks * 4 + quad) ^ (row & 15)) * 8)];
#pragma unroll
          for (int mi = 0; mi < 2; mi++) {
            frag_cd acc = (frag_cd){0.f, 0.f, 0.f, 0.f};
#pragma unroll
            for (int ks = 0; ks < 4; ks++)
              acc = __builtin_amdgcn_mfma_f32_16x16x32_bf16(qf[mi][ks], kf[ks], acc, 0, 0, 0);
            int colg = kv0 + nj * 16 + l16;
#pragma unroll
            for (int r = 0; r < 4; r++) {
              int rowg = q0 + mi * 16 + quad * 4 + r;
              p[mi][nj][r] = (colg <= rowg) ? acc[r] : -10000.0f;
            }
          }
        }
        __builtin_amdgcn_s_setprio(0);

        // online softmax (stats per q-row at lanes (quad,r), reduce over l16)
#pragma unroll
        for (int mi = 0; mi < 2; mi++) {
#pragma unroll
          for (int r = 0; r < 4; r++) {
            float mx = fmaxf(fmaxf(p[mi][0][r], p[mi][1][r]), fmaxf(p[mi][2][r], p[mi][3][r]));
#pragma unroll
            for (int off = 1; off < 16; off <<= 1)
              mx = fmaxf(mx, __shfl_xor(mx, off, 64));
            float mnew  = fmaxf(m_i[mi][r], mx);
            float alpha = __expf(m_i[mi][r] - mnew);
            float rs = 0.f;
#pragma unroll
            for (int nj = 0; nj < 4; nj++) {
              float e = __expf(p[mi][nj][r] - mnew);
              p[mi][nj][r] = e;
              rs += e;
            }
#pragma unroll
            for (int off = 1; off < 16; off <<= 1)
              rs += __shfl_xor(rs, off, 64);
            l_i[mi][r] = l_i[mi][r] * alpha + rs;
            m_i[mi][r] = mnew;
#pragma unroll
            for (int ni = 0; ni < 8; ni++) o[mi][ni][r] *= alpha;
          }
        }

        // P (C-layout) -> LDS (A-layout source), padded rows; per-wave buffer
#pragma unroll
        for (int mi = 0; mi < 2; mi++)
#pragma unroll
          for (int nj = 0; nj < 4; nj++)
#pragma unroll
            for (int r = 0; r < 4; r++)
              pw[(mi * 16 + quad * 4 + r) * 72 + nj * 16 + l16] = f2b(p[mi][nj][r]);

        // O += P @ V  (pf from padded Ps; vf from swizzled Vs, GEMM bf-pattern)
        __builtin_amdgcn_s_setprio(1);
#pragma unroll
        for (int ni = 0; ni < 8; ni++) {
          int vrow = ni * 16 + l16;
          frag_ab vf0 = *(const frag_ab*)&Vs[vrow * 64 + ((quad ^ (l16 & 7)) * 8)];
          frag_ab vf1 = *(const frag_ab*)&Vs[vrow * 64 + (((quad + 4) ^ (l16 & 7)) * 8)];
#pragma unroll
          for (int mi = 0; mi < 2; mi++) {
            frag_ab pf0 = *(const frag_ab*)&pw[(mi * 16 + l16) * 72 + quad * 8];
            frag_ab pf1 = *(const frag_ab*)&pw[(mi * 16 + l16) * 72 + 32 + quad * 8];
            o[mi][ni] = __builtin_amdgcn_mfma_f32_16x16x32_bf16(pf0, vf0, o[mi][ni], 0, 0, 0);
            o[mi][ni] = __builtin_amdgcn_mfma_f32_16x16x32_bf16(pf1, vf1, o[mi][ni], 0, 0, 0);
          }
        }
        __builtin_amdgcn_s_setprio(0);
      }
    }

    // ctx row-major (B,S,E)
#pragma unroll
    for (int mi = 0; mi < 2; mi++) {
#pragma unroll
      for (int r = 0; r < 4; r++) {
        float inv = 1.0f / fmaxf(l_i[mi][r], 1.0e-20f);
        int s = q0 + mi * 16 + quad * 4 + r;
        long rowb = ((long)b * 2048 + s) * 2048 + h * 128;
#pragma unroll
        for (int ni = 0; ni < 8; ni++)
          ctx[rowb + ni * 16 + l16] = f2b(o[mi][ni][r] * inv);
      }
    }
  }
}

// ---------------------------------------------------------------------------
// GEMM2: out(f32) = ctx(bf16 row-major) @ wo^T + wo_b
// ---------------------------------------------------------------------------
__global__ __launch_bounds__(256)
void gemm_ctx(const unsigned short* __restrict__ A,
              const float* __restrict__ Bw,
              const unsigned short* __restrict__ Bbf,
              const float* __restrict__ bias,
              float* __restrict__ C) {
  __shared__ __align__(16) unsigned short As[128 * 64];
  __shared__ __align__(16) unsigned short Bs[128 * 64];
  const int tid  = threadIdx.x;
  const int wave = tid >> 6, lane = tid & 63;
  const int quad = lane >> 4, l16 = lane & 15;
  const int wm = (wave & 1) * 64, wn = (wave >> 1) * 64;
  const int row0A = blockIdx.x * 128;
  const int row0B = blockIdx.y * 128;

  frag_cd acc[4][4];
#pragma unroll
  for (int i = 0; i < 4; i++)
#pragma unroll
    for (int j = 0; j < 4; j++) acc[i][j] = (frag_cd){0.f, 0.f, 0.f, 0.f};

  for (int k0 = 0; k0 < 2048; k0 += 64) {
    stage_a_async(A, As, row0A, k0, wave, lane, 2048);
    if (Bbf) stage_a_async(Bbf, Bs, row0B, k0, wave, lane, 2048);
    else     stage_b_cvt(Bw, Bs, row0B, k0, tid);
    __syncthreads();
#pragma unroll
    for (int kk = 0; kk < 64; kk += 32) {
      frag_ab af[4], bf[4];
#pragma unroll
      for (int mi = 0; mi < 4; mi++) {
        int row = wm + mi * 16 + l16;
        af[mi] = *(const frag_ab*)&As[row * 64 + (((quad + (kk >> 3)) ^ (l16 & 7)) * 8)];
      }
#pragma unroll
      for (int ni = 0; ni < 4; ni++) {
        int row = wn + ni * 16 + l16;
        bf[ni] = *(const frag_ab*)&Bs[row * 64 + (((quad + (kk >> 3)) ^ (l16 & 7)) * 8)];
      }
#pragma unroll
      for (int mi = 0; mi < 4; mi++)
#pragma unroll
        for (int ni = 0; ni < 4; ni++)
          acc[mi][ni] = __builtin_amdgcn_mfma_f32_16x16x32_bf16(af[mi], bf[ni], acc[mi][ni], 0, 0, 0);
    }
    __syncthreads();
  }
#pragma unroll
  for (int ni = 0; ni < 4; ni++) {
    int col = row0B + wn + ni * 16 + l16;
    float bv = bias[col];
#pragma unroll
    for (int mi = 0; mi < 4; mi++) {
#pragma unroll
      for (int r = 0; r < 4; r++) {
        int row = row0A + wm + mi * 16 + quad * 4 + r;
        C[(long)row * 2048 + col] = acc[mi][ni][r] + bv;
      }
    }
  }
}

// ---------------------------------------------------------------------------
extern "C" void kernel_launch(void* const* d_in, const int* in_sizes, int n_in,
                              void* d_out, int out_size, void* d_ws, size_t ws_size,
                              hipStream_t stream) {
  const float* x      = (const float*)d_in[0];
  const float* wqkv_w = (const float*)d_in[1];
  const float* wqkv_b = (const float*)d_in[2];
  const float* wo_w   = (const float*)d_in[3];
  const float* wo_b   = (const float*)d_in[4];

  unsigned short* xb  = (unsigned short*)d_out;              // [0,32MiB)
  unsigned short* Qb  = (unsigned short*)d_out + 16777216;   // [32,64MiB)
  unsigned short* Kb  = (unsigned short*)d_ws;               // ws [0,32MiB)
  unsigned short* Vt  = (unsigned short*)d_ws + 16777216;    // ws [32,64MiB)
  unsigned short* ctx = (unsigned short*)d_out;              // over xb (dead)
  float* outf = (float*)d_ws;                                // ws [0,64MiB)

  const bool big = ws_size >= 100663296UL;  // 96 MiB: room for bf16 weights
  unsigned short* Wq = big ? (unsigned short*)d_ws + 33554432 : nullptr; // [64,88MiB)
  unsigned short* Wo = big ? (unsigned short*)d_ws + 46137344 : nullptr; // [88,96MiB)

  // 0) conversions
  cvt_f32_bf16<<<8192, 256, 0, stream>>>(x, xb);
  if (big) {
    cvt_f32_bf16<<<6144, 256, 0, stream>>>(wqkv_w, Wq);
    cvt_f32_bf16<<<2048, 256, 0, stream>>>(wo_w, Wo);
  }
  // 1) QKV projection -> Q,K (bhsd), V^T (bhds)
  gemm_qkv<<<dim3(64, 48), 256, 0, stream>>>(xb, wqkv_w, Wq, wqkv_b, Qb, Kb, Vt);
  // 2) rope in place (folds attn scale into Q)
  rope_inplace<<<65536, 256, 0, stream>>>(Qb, Kb);
  // 3) flash attention, paired q-tiles -> ctx (B,S,E) bf16
  attn_fwd<<<dim3(64, 8), 256, 0, stream>>>(Qb, Kb, Vt, ctx);
  // 4) output projection -> f32 ws, copy back
  gemm_ctx<<<dim3(64, 16), 256, 0, stream>>>(ctx, wo_w, Wo, wo_b, outf);
  hipMemcpyAsync(d_out, outf, 67108864UL, hipMemcpyDeviceToDevice, stream);
}